// Round 10
// baseline (241.641 us; speedup 1.0000x reference)
//
#include <hip/hip_runtime.h>

#define BB 2
#define SS 2048
#define DDIM 1024
#define HH 16
#define DEPTH 64
#define QKVN (3*DDIM)

typedef unsigned short u16;
typedef unsigned int u32;
typedef __attribute__((ext_vector_type(8))) short bf16x8;
typedef __attribute__((ext_vector_type(4))) float f32x4;

__device__ __forceinline__ u16 f2bf(float f){
  union{float f; u32 u;} z; z.f=f;
  u32 r = z.u + 0x7fffu + ((z.u>>16)&1u);
  return (u16)(r>>16);
}
#define NEG_BIG (-1e30f)

// async global->LDS 16B DMA (m97 pattern). LDS dest MUST be wave-uniform
// base + lane*16 in lane order — all call sites below satisfy this.
typedef const __attribute__((address_space(1))) u32* gas_t;
typedef __attribute__((address_space(3))) u32* las_t;
__device__ __forceinline__ void gl_lds16(const void* g, void* l){
  __builtin_amdgcn_global_load_lds((gas_t)g, (las_t)l, 16, 0, 0);
}

// ---------------- transpose+convert f32 [R,C] -> bf16 [C,R] ----------------
__global__ void convT_k(const float* __restrict__ in, u16* __restrict__ out, int R, int C){
  __shared__ float tile[32][33];
  int c0 = blockIdx.x<<5, r0 = blockIdx.y<<5;
  int tx = threadIdx.x, ty = threadIdx.y;
  for (int i=ty;i<32;i+=8) tile[i][tx] = in[(size_t)(r0+i)*C + c0+tx];
  __syncthreads();
  for (int i=ty;i<32;i+=8) out[(size_t)(c0+i)*R + r0+tx] = f2bf(tile[tx][i]);
}

// ---------------- convert f32 -> bf16 flat (both batches) ----------------
__global__ void convX_k(const float* __restrict__ in, u16* __restrict__ out){
  size_t i = ((size_t)blockIdx.x*256 + threadIdx.x) * 8;
  float4 a = *(const float4*)(in + i);
  float4 b = *(const float4*)(in + i + 4);
  ushort4 lo = { f2bf(a.x), f2bf(a.y), f2bf(a.z), f2bf(a.w) };
  ushort4 hi = { f2bf(b.x), f2bf(b.y), f2bf(b.z), f2bf(b.w) };
  *(ushort4*)(out + i)     = lo;
  *(ushort4*)(out + i + 4) = hi;
}

// ---------------- QKV GEMM (m97 bf16 MFMA + global_load_lds) ----------------
// Both batches: [4096,1024]@[1024,3072]^T. LDS staging offset = tid*16 bytes
// (row=c>>2, off=(c&3)*8 -> element c*8), lane-contiguous per wave.
__global__ __launch_bounds__(256,2) void gemm_qkv_k(
    const u16* __restrict__ A, const u16* __restrict__ Bt,
    const float* __restrict__ bias,
    u16* __restrict__ Qb, u16* __restrict__ Kb, u16* __restrict__ Vt)
{
  const int K = DDIM;
  __shared__ __align__(16) u16 As[128*32];
  __shared__ __align__(16) u16 Bs[128*32];
  const int tid = threadIdx.x;
  const int m0 = blockIdx.x<<7, n0 = blockIdx.y<<7;
  const int w = tid>>6, lane = tid&63, q = lane>>4, ln = lane&15;
  const int wr = (w>>1)<<6, wc = (w&1)<<6;

  f32x4 acc[4][4];
  #pragma unroll
  for (int i=0;i<4;i++)
    #pragma unroll
    for (int j=0;j<4;j++) acc[i][j] = (f32x4){0.f,0.f,0.f,0.f};

  for (int k0=0;k0<K;k0+=32){
    {
      int c = tid, row = c>>2, off = (c&3)<<3;
      gl_lds16(&A [(size_t)(m0+row)*K + k0 + off], &As[c<<3]);
      gl_lds16(&Bt[(size_t)(n0+row)*K + k0 + off], &Bs[c<<3]);
      c = tid + 256; row = c>>2; off = (c&3)<<3;
      gl_lds16(&A [(size_t)(m0+row)*K + k0 + off], &As[c<<3]);
      gl_lds16(&Bt[(size_t)(n0+row)*K + k0 + off], &Bs[c<<3]);
    }
    __syncthreads();
    bf16x8 af[4], bfr[4];
    #pragma unroll
    for (int i=0;i<4;i++) af[i]  = *(const bf16x8*)&As[((wr + (i<<4) + ln)<<5) + (q<<3)];
    #pragma unroll
    for (int j=0;j<4;j++) bfr[j] = *(const bf16x8*)&Bs[((wc + (j<<4) + ln)<<5) + (q<<3)];
    #pragma unroll
    for (int i=0;i<4;i++)
      #pragma unroll
      for (int j=0;j<4;j++)
        acc[i][j] = __builtin_amdgcn_mfma_f32_16x16x32_bf16(af[i], bfr[j], acc[i][j], 0, 0, 0);
    __syncthreads();
  }

  #pragma unroll
  for (int i=0;i<4;i++){
    const int mmb = m0 + wr + (i<<4) + (q<<2);         // global row (4096 range)
    const int bsel = mmb >> 11;                        // batch (uniform per block)
    const int sb   = mmb & 2047;                       // s within batch
    #pragma unroll
    for (int j=0;j<4;j++){
      const int n = n0 + wc + (j<<4) + ln;
      const int h = n / 192;
      const int rr = n - h*192;
      const int bh = (bsel<<4) + h;
      const float bv = bias[n];
      if (rr < 64){                                    // Q, scaled by 1/8
        u16* dst = Qb + (size_t)bh*SS*DEPTH + rr;
        #pragma unroll
        for (int r=0;r<4;r++) dst[(size_t)(sb+r)*DEPTH] = f2bf((acc[i][j][r] + bv)*0.125f);
      } else if (rr < 128){                            // K
        u16* dst = Kb + (size_t)bh*SS*DEPTH + (rr-64);
        #pragma unroll
        for (int r=0;r<4;r++) dst[(size_t)(sb+r)*DEPTH] = f2bf(acc[i][j][r] + bv);
      } else {                                         // V transposed: Vt[bh][d][s]
        ushort4 pv = { f2bf(acc[i][j][0] + bv), f2bf(acc[i][j][1] + bv),
                       f2bf(acc[i][j][2] + bv), f2bf(acc[i][j][3] + bv) };
        *(ushort4*)(Vt + ((size_t)bh*DEPTH + (rr-128))*SS + sb) = pv;
      }
    }
  }
}

// ---------------- MFMA flash attention, global_load_lds staging ----------------
// Grid (32 bh, 32 slots); slot->qt permutation balances per-CU work; bh%8 = XCD.
// Ks/VsT stride 64 (padding proven irrelevant in R8) -> staging LDS offset =
// (p*256+tid)*16 bytes, lane-contiguous -> DMA direct, no VGPR round trip.
__global__ __launch_bounds__(256,4) void attn_k(
    u16* __restrict__ Qb, const u16* __restrict__ Kb, const u16* __restrict__ Vt)
{
  __shared__ __align__(16) u16 Ks[64*64];      // K tile [j][d]
  __shared__ __align__(16) u16 VsT[64*64];     // V^T tile [d][j]
  __shared__ __align__(16) u16 ps[4][16*72];   // per-wave P [m][j], stride 72

  const int tid = threadIdx.x, w = tid>>6, lane = tid&63, q = lane>>4, ln = lane&15;
  const int bh = blockIdx.x;                   // b*16 + h  (XCD = bh%8)
  const int y  = blockIdx.y, sgrp = y>>3, rr_ = y&7;
  const int qt = (sgrp==0) ? 31-rr_ : (sgrp==1) ? 16+rr_ : (sgrp==2) ? 15-rr_ : rr_;
  const int r0 = qt<<6;
  const size_t kbase = (size_t)bh*SS*DEPTH;    // Kb/Qb per-(b,h) base
  const size_t vbase = (size_t)bh*DEPTH*SS;    // Vt per-(b,h) base

  bf16x8 qf[2];
  #pragma unroll
  for (int ks=0;ks<2;ks++)
    qf[ks] = *(const bf16x8*)(Qb + kbase + (size_t)(r0 + (w<<4) + ln)*DEPTH + (ks<<5) + (q<<3));

  f32x4 o[4];
  #pragma unroll
  for (int nt=0;nt<4;nt++) o[nt] = (f32x4){0.f,0.f,0.f,0.f};
  float m_r[4], l_r[4];
  #pragma unroll
  for (int r=0;r<4;r++){ m_r[r] = NEG_BIG; l_r[r] = 0.f; }

  const int T = qt + 1;
  for (int t=0;t<T;t++){
    __syncthreads();                           // prior tile's Ks/VsT/ps reads done
    #pragma unroll
    for (int p=0;p<2;p++){
      const int e = (p*256 + tid)*8;           // element index; LDS byte off = e*2
      gl_lds16(Kb + kbase + (size_t)(t<<6)*DEPTH + e, &Ks[e]);       // fully linear
      const int j = e>>6, d = e&63;
      gl_lds16(Vt + vbase + (size_t)j*SS + (t<<6) + d, &VsT[e]);
    }
    __syncthreads();                           // drains DMA (vmcnt) + all waves

    // QK^T
    f32x4 sc[4];
    #pragma unroll
    for (int jt=0;jt<4;jt++) sc[jt] = (f32x4){0.f,0.f,0.f,0.f};
    #pragma unroll
    for (int ks=0;ks<2;ks++){
      #pragma unroll
      for (int jt=0;jt<4;jt++){
        bf16x8 kf = *(const bf16x8*)&Ks[(((jt<<4)+ln)<<6) + (ks<<5) + (q<<3)];
        sc[jt] = __builtin_amdgcn_mfma_f32_16x16x32_bf16(qf[ks], kf, sc[jt], 0, 0, 0);
      }
    }

    // causal mask on diagonal tile
    if (t == T-1){
      const int rowb = r0 + (w<<4) + (q<<2);
      #pragma unroll
      for (int jt=0;jt<4;jt++){
        const int col = (t<<6) + (jt<<4) + ln;
        #pragma unroll
        for (int r=0;r<4;r++)
          if (col > rowb + r) sc[jt][r] = NEG_BIG;
      }
    }

    // online softmax per row (row lives on 16 lanes sharing quad q)
    float alpha_r[4];
    #pragma unroll
    for (int r=0;r<4;r++){
      float mt = fmaxf(fmaxf(sc[0][r], sc[1][r]), fmaxf(sc[2][r], sc[3][r]));
      #pragma unroll
      for (int off=1; off<16; off<<=1) mt = fmaxf(mt, __shfl_xor(mt, off));
      const float mnew = fmaxf(m_r[r], mt);
      alpha_r[r] = __expf(m_r[r] - mnew);
      float p0 = __expf(sc[0][r]-mnew), p1 = __expf(sc[1][r]-mnew);
      float p2 = __expf(sc[2][r]-mnew), p3 = __expf(sc[3][r]-mnew);
      const int mrow = (q<<2) + r;
      ps[w][mrow*72 +      ln] = f2bf(p0);
      ps[w][mrow*72 + 16 + ln] = f2bf(p1);
      ps[w][mrow*72 + 32 + ln] = f2bf(p2);
      ps[w][mrow*72 + 48 + ln] = f2bf(p3);
      float psum = (p0+p1)+(p2+p3);
      #pragma unroll
      for (int off=1; off<16; off<<=1) psum += __shfl_xor(psum, off);
      l_r[r] = l_r[r]*alpha_r[r] + psum;
      m_r[r] = mnew;
    }
    #pragma unroll
    for (int nt=0;nt<4;nt++)
      #pragma unroll
      for (int r=0;r<4;r++) o[nt][r] *= alpha_r[r];

    __syncthreads();                           // ps visible/ordered before PV reads

    // PV
    #pragma unroll
    for (int ks=0;ks<2;ks++){
      bf16x8 pa = *(const bf16x8*)&ps[w][ln*72 + (ks<<5) + (q<<3)];
      #pragma unroll
      for (int nt=0;nt<4;nt++){
        bf16x8 vf = *(const bf16x8*)&VsT[(((nt<<4)+ln)<<6) + (ks<<5) + (q<<3)];
        o[nt] = __builtin_amdgcn_mfma_f32_16x16x32_bf16(pa, vf, o[nt], 0, 0, 0);
      }
    }
  }

  // epilogue: o/l -> bf16, overwrite this block's own Qb rows
  #pragma unroll
  for (int r=0;r<4;r++){
    const float rl = 1.f / fmaxf(l_r[r], 1e-30f);
    const int s = r0 + (w<<4) + (q<<2) + r;
    #pragma unroll
    for (int nt=0;nt<4;nt++)
      Qb[kbase + (size_t)s*DEPTH + (nt<<4) + ln] = f2bf(o[nt][r] * rl);
  }
}

// ---------------- out projection (m97 bf16 MFMA + global_load_lds), f32 out --------
// A(m,k) = Qb[(m>>11)*16 + k/64][m&2047][k%64]
__global__ __launch_bounds__(256,2) void gemm_out_k(
    const u16* __restrict__ Aq, const u16* __restrict__ Bt,
    const float* __restrict__ bias, float* __restrict__ out)
{
  const int K = DDIM;
  __shared__ __align__(16) u16 As[128*32];
  __shared__ __align__(16) u16 Bs[128*32];
  const int tid = threadIdx.x;
  const int m0 = blockIdx.x<<7, n0 = blockIdx.y<<7;
  const int bsel = m0>>11, ms = m0&2047;       // batch select (uniform per block)
  const int w = tid>>6, lane = tid&63, q = lane>>4, ln = lane&15;
  const int wr = (w>>1)<<6, wc = (w&1)<<6;

  f32x4 acc[4][4];
  #pragma unroll
  for (int i=0;i<4;i++)
    #pragma unroll
    for (int j=0;j<4;j++) acc[i][j] = (f32x4){0.f,0.f,0.f,0.f};

  for (int k0=0;k0<K;k0+=32){
    const size_t abase = (size_t)((bsel<<4) + (k0>>6))*SS*DEPTH + (k0&63);
    {
      int c = tid, row = c>>2, off = (c&3)<<3;
      gl_lds16(&Aq[abase + (size_t)(ms+row)*DEPTH + off], &As[c<<3]);
      gl_lds16(&Bt[(size_t)(n0+row)*K + k0 + off],        &Bs[c<<3]);
      c = tid + 256; row = c>>2; off = (c&3)<<3;
      gl_lds16(&Aq[abase + (size_t)(ms+row)*DEPTH + off], &As[c<<3]);
      gl_lds16(&Bt[(size_t)(n0+row)*K + k0 + off],        &Bs[c<<3]);
    }
    __syncthreads();
    bf16x8 af[4], bfr[4];
    #pragma unroll
    for (int i=0;i<4;i++) af[i]  = *(const bf16x8*)&As[((wr + (i<<4) + ln)<<5) + (q<<3)];
    #pragma unroll
    for (int j=0;j<4;j++) bfr[j] = *(const bf16x8*)&Bs[((wc + (j<<4) + ln)<<5) + (q<<3)];
    #pragma unroll
    for (int i=0;i<4;i++)
      #pragma unroll
      for (int j=0;j<4;j++)
        acc[i][j] = __builtin_amdgcn_mfma_f32_16x16x32_bf16(af[i], bfr[j], acc[i][j], 0, 0, 0);
    __syncthreads();
  }

  #pragma unroll
  for (int i=0;i<4;i++){
    #pragma unroll
    for (int j=0;j<4;j++){
      const int n = n0 + wc + (j<<4) + ln;
      const float bv = bias[n];
      #pragma unroll
      for (int r=0;r<4;r++){
        const int mm = m0 + wr + (i<<4) + (q<<2) + r;
        out[(size_t)mm*DDIM + n] = acc[i][j][r] + bv;
      }
    }
  }
}

extern "C" void kernel_launch(void* const* d_in, const int* in_sizes, int n_in,
                              void* d_out, int out_size, void* d_ws, size_t ws_size,
                              hipStream_t stream)
{
  int ix = 0, iw = 2, ibq = 3, iwo = 4, ibo = 5;
  if (n_in == 5){ iw = 1; ibq = 2; iwo = 3; ibo = 4; }
  const float* x  = (const float*)d_in[ix];
  const float* Wq = (const float*)d_in[iw];
  const float* bq = (const float*)d_in[ibq];
  const float* Wo = (const float*)d_in[iwo];
  const float* bo = (const float*)d_in[ibo];
  float* out = (float*)d_out;

  // workspace (u16 units), total 41,943,040 B — round-1-proven footprint
  u16* ws  = (u16*)d_ws;
  u16* Wqt = ws;                                   // [3072,1024] bf16
  u16* Wot = Wqt + (size_t)QKVN*DDIM;              // [1024,1024] bf16 (bt form)
  u16* Qb  = Wot + (size_t)DDIM*DDIM;              // [B*H][S][64]; attn out aliases here
  u16* Kb  = Qb  + (size_t)BB*HH*SS*DEPTH;         // [B*H][S][64]
  u16* Vt  = Kb  + (size_t)BB*HH*SS*DEPTH;         // [B*H][64][S] (V transposed)
  u16* xb  = Vt  + (size_t)BB*HH*SS*DEPTH;         // [2,2048,1024] bf16

  convT_k<<<dim3(QKVN/32, DDIM/32), dim3(32,8), 0, stream>>>(Wq, Wqt, DDIM, QKVN);
  convT_k<<<dim3(DDIM/32, DDIM/32), dim3(32,8), 0, stream>>>(Wo, Wot, DDIM, DDIM);
  convX_k<<<dim3(BB*SS*DDIM/2048), 256, 0, stream>>>(x, xb);

  gemm_qkv_k<<<dim3(BB*SS/128, QKVN/128), 256, 0, stream>>>(xb, Wqt, bq, Qb, Kb, Vt);
  attn_k    <<<dim3(BB*HH, 32),           256, 0, stream>>>(Qb, Kb, Vt);
  gemm_out_k<<<dim3(BB*SS/128, DDIM/128), 256, 0, stream>>>(Qb, Wot, bo, out);
}